// Round 1
// baseline (94.558 us; speedup 1.0000x reference)
//
#include <hip/hip_runtime.h>

// Forward-pass analysis: quantize_pot_ste clips mem to <= 127/128 < THRESHOLD=1.0,
// so the hard spike (mem >= 1.0) never fires; forward output is identically zero
// (incl. reg_loss). Kernel = vectorized zero-fill of d_out (poisoned 0xAA by harness).

__global__ __launch_bounds__(256) void zero_fill_kernel(float4* __restrict__ out4,
                                                        long long n4,
                                                        float* __restrict__ out,
                                                        long long n) {
    long long i = (long long)blockIdx.x * blockDim.x + threadIdx.x;
    if (i < n4) {
        out4[i] = make_float4(0.f, 0.f, 0.f, 0.f);
    }
    // tail elements (n % 4): first few threads also write scalar tail
    long long t = n4 * 4 + i;
    if (t < n) {
        out[t] = 0.f;
    }
}

extern "C" void kernel_launch(void* const* d_in, const int* in_sizes, int n_in,
                              void* d_out, int out_size, void* d_ws, size_t ws_size,
                              hipStream_t stream) {
    (void)d_in; (void)in_sizes; (void)n_in; (void)d_ws; (void)ws_size;
    long long n = (long long)out_size;        // 16*256*5000 + 1 = 20,480,001
    long long n4 = n / 4;                     // 5,120,000 float4 stores
    int block = 256;
    long long grid = (n4 + block - 1) / block; // 20,000 blocks
    zero_fill_kernel<<<(dim3)(unsigned)grid, block, 0, stream>>>(
        (float4*)d_out, n4, (float*)d_out, n);
}